// Round 9
// baseline (70.128 us; speedup 1.0000x reference)
//
#include <hip/hip_runtime.h>
#include <hip/hip_bf16.h>

typedef __attribute__((ext_vector_type(8))) short bf16x8;
typedef __attribute__((ext_vector_type(4))) float f32x4;
typedef __attribute__((ext_vector_type(2))) float f32x2;

constexpr int P = 8192, C = 8192, D = 256;

__device__ __forceinline__ void gload_lds16(const void* g, void* l) {
    __builtin_amdgcn_global_load_lds((const __attribute__((address_space(1))) void*)g,
                                     (__attribute__((address_space(3))) void*)l, 16, 0, 0);
}

__device__ __forceinline__ unsigned short bfbits(float f) {
    __hip_bfloat16 h = __float2bfloat16(f);
    return __builtin_bit_cast(unsigned short, h);
}

// Normalize rows to unit L2 norm, store bf16. One wave per row, float4 loads.
__global__ __launch_bounds__(256) void prep_kernel(const float* __restrict__ prev,
                                                   const float* __restrict__ cur,
                                                   unsigned short* __restrict__ prevb,
                                                   unsigned short* __restrict__ curb) {
    const int lane = threadIdx.x & 63;
    const int wv = threadIdx.x >> 6;
    const int row = blockIdx.x * 4 + wv;
    const float* src;
    unsigned short* dst;
    int r;
    if (row < P) { src = prev; dst = prevb; r = row; }
    else         { src = cur;  dst = curb;  r = row - P; }
    const float4 v = *(const float4*)(src + (size_t)r * D + lane * 4);
    float ss = v.x * v.x + v.y * v.y + v.z * v.z + v.w * v.w;
#pragma unroll
    for (int off = 32; off; off >>= 1) ss += __shfl_xor(ss, off, 64);
    const float inv = 1.0f / sqrtf(ss);   // norms ~16; eps=1e-6 unreachable
    ushort4 o;
    o.x = bfbits(v.x * inv);
    o.y = bfbits(v.y * inv);
    o.z = bfbits(v.z * inv);
    o.w = bfbits(v.w * inv);
    *(ushort4*)(dst + (size_t)r * D + lane * 4) = o;
}

// Fat-tile hybrid GEMM (r6-r8 all capped at 28% MfmaUtil = per-wave duty
// limit of thin 32x32 tiles). Here: 8 waves x (128x64) tile -> 32 MFMA
// (~515 pipe-cyc) per wave-step between stall points. A (256 rows x full K)
// lives in 128 KB LDS, staged ONCE (counted vmcnt, barriers only in the
// first 8 steps); B fragments are register-direct from L2 (16-row x 64B
// gathers, 3-bank rotation, issued 2 steps ahead). Steps 8..31 have NO
// barriers: pure ds_read/MFMA/B-load stream. LDS demand ~750cy/step <
// MFMA 1030cy/step -> MFMA-bound by construction. Epilogue per col-tile
// overlaps the other SIMD-wave's MFMAs.
__global__ __attribute__((amdgpu_flat_work_group_size(512, 512), amdgpu_waves_per_eu(2, 2)))
void gemm_bce_kernel(
    const unsigned short* __restrict__ Ab, const unsigned short* __restrict__ Bb,
    const int* __restrict__ pids, const int* __restrict__ cids,
    float* __restrict__ partial) {
    __shared__ short sA[8][256][32];   // 128 KB: [ktile][row][k-granules], swizzled
    __shared__ float wsum[8];

    const int tid = threadIdx.x;
    const int lane = tid & 63;
    const int wv = tid >> 6;          // 0..7
    const int wm = wv >> 2;           // 0..1  (M half)
    const int wn = wv & 3;            // 0..3  (N quarter)

    // XCD-aware decode: each XCD gets an 8(by) x 4(bxx) slab (A 1MB + B 2MB in L2)
    const int bid = blockIdx.x;
    const int xcd = bid & 7, kk = bid >> 3;        // kk 0..31
    const int pblock = ((xcd >> 1) * 8 + (kk & 7)) * 256;
    const int cbase = (((xcd & 1) * 4) + (kk >> 3)) * 1024;

    // ---- pids first (drained so the vmcnt ledger below is stage-only) ----
    int pidp[16];
#pragma unroll
    for (int m = 0; m < 8; ++m)
#pragma unroll
        for (int rp = 0; rp < 2; ++rp) {
            const int base = pblock + wm * 128 + m * 16 + (lane >> 4) * 4 + rp * 2;
            pidp[m * 2 + rp] = (pids[base] & 0xffff) | (pids[base + 1] << 16);
        }
    asm volatile("s_waitcnt vmcnt(0)" ::: "memory");

    // ---- A staging: thread covers rows r*128+(tid>>2), granule tid&3.
    // Swizzle g' = g ^ ((row>>1)&3) (both-sides involution; LDS linear dest).
    const int sg = (tid & 3) ^ ((tid >> 3) & 3);
    auto stageA = [&](int kt) {
#pragma unroll
        for (int r = 0; r < 2; ++r) {
            const int row = r * 128 + (tid >> 2);
            gload_lds16(Ab + (size_t)(pblock + row) * D + kt * 32 + sg * 8,
                        &sA[kt][0][0] + (r * 512 + tid) * 8);
        }
    };

    // B fragment: register-direct from global (L2). 16B/lane, 16-row gather.
    auto loadB = [&](int s, int j) -> bf16x8 {
        return *(const bf16x8*)(Bb
            + (size_t)(cbase + (s >> 3) * 256 + wn * 64 + j * 16 + (lane & 15)) * D
            + (s & 7) * 32 + (lane >> 4) * 8);
    };

    // A-frag per-lane offset (elems): row (lane&15), phys granule (lane>>4)^swz
    const int aoff = (lane & 15) * 32 + (((lane >> 4) ^ ((lane >> 1) & 3)) * 8);

    bf16x8 bfr[3][4];
    // Prologue: A0, B0, A1, B1 (12 loads; boundary-0 keeps {A1,B1}=6 in flight)
    stageA(0);
#pragma unroll
    for (int j = 0; j < 4; ++j) bfr[0][j] = loadB(0, j);
    stageA(1);
#pragma unroll
    for (int j = 0; j < 4; ++j) bfr[1][j] = loadB(1, j);

    // ln(2cosh(x/2)) - ln2 = t/8 - t^2/192 + t^3/2880 - 17t^4/645120, t=x^2
    constexpr float C1 = 0.125f, C2 = -5.2083333e-3f, C3 = 3.4722222e-4f, C4 = -2.6354832e-5f;
    f32x2 sh2 = {0.f, 0.f}, sx2 = {0.f, 0.f};

#pragma unroll
    for (int ct = 0; ct < 4; ++ct) {
        f32x4 acc[8][4] = {};
#pragma unroll
        for (int ks = 0; ks < 8; ++ks) {
            const int s = ct * 8 + ks;
            // Counted waits + barriers only while A is being staged (s<8).
            if (s < 7) {
                asm volatile("s_waitcnt vmcnt(6)" ::: "memory");
                asm volatile("s_barrier" ::: "memory");
            } else if (s == 7) {
                asm volatile("s_waitcnt vmcnt(4)" ::: "memory");
                asm volatile("s_barrier" ::: "memory");
            }
            asm volatile("" ::: "memory");   // per-step ordering point (anti-hoist)
            bf16x8 afr[8];
#pragma unroll
            for (int m = 0; m < 8; ++m)
                afr[m] = *(const bf16x8*)(&sA[s & 7][wm * 128 + m * 16][0] + aoff);
            if (s < 6) stageA(s + 2);
            if (s < 30) {
#pragma unroll
                for (int j = 0; j < 4; ++j) bfr[(s + 2) % 3][j] = loadB(s + 2, j);
            }
            __builtin_amdgcn_s_setprio(1);
#pragma unroll
            for (int m = 0; m < 8; ++m)
#pragma unroll
                for (int j = 0; j < 4; ++j)
                    acc[m][j] = __builtin_amdgcn_mfma_f32_16x16x32_bf16(
                        afr[m], bfr[s % 3][j], acc[m][j], 0, 0, 0);
            __builtin_amdgcn_s_setprio(0);
        }
        // ---- fused BCE epilogue for col-tile ct (VALU only; no barrier) ----
        // C/D layout: col=lane&15, row=(lane>>4)*4+reg (m89-verified).
        const int c0 = cbase + ct * 256 + wn * 64 + (lane & 15);
        int cid_r[4];
#pragma unroll
        for (int j = 0; j < 4; ++j) cid_r[j] = cids[c0 + j * 16];
#pragma unroll
        for (int m = 0; m < 8; ++m)
#pragma unroll
            for (int j = 0; j < 4; ++j)
#pragma unroll
                for (int rp = 0; rp < 2; ++rp) {
                    const f32x2 x = {acc[m][j][rp * 2], acc[m][j][rp * 2 + 1]};
                    const f32x2 t2 = x * x;
                    f32x2 q = t2 * C4 + C3;
                    q = t2 * q + C2;
                    q = t2 * q + C1;
                    sh2 = t2 * q + sh2;
                    const int pp = pidp[m * 2 + rp];
                    const f32x2 cc = {
                        ((pp & 0xffff) == cid_r[j]) ? -0.5f : 0.5f,
                        ((pp >> 16)    == cid_r[j]) ? -0.5f : 0.5f};
                    sx2 = x * cc + sx2;
                }
    }

    float lsum = sh2.x + sh2.y + sx2.x + sx2.y;
#pragma unroll
    for (int off = 32; off; off >>= 1) lsum += __shfl_xor(lsum, off, 64);
    if (lane == 0) wsum[wv] = lsum;
    __syncthreads();
    if (tid == 0) {
        float b = 0.f;
#pragma unroll
        for (int w = 0; w < 8; ++w) b += wsum[w];
        partial[bid] = b;
    }
}

// Deterministic final reduction over 256 block partials; adds folded ln2.
__global__ __launch_bounds__(256) void reduce_kernel(const float* __restrict__ part,
                                                     float* __restrict__ out) {
    const int tid = threadIdx.x;
    double s = (tid < 256) ? (double)part[tid] : 0.0;
#pragma unroll
    for (int off = 32; off; off >>= 1) s += __shfl_xor(s, off, 64);
    __shared__ double red[4];
    const int lane = tid & 63, wv = tid >> 6;
    if (lane == 0) red[wv] = s;
    __syncthreads();
    if (tid == 0)
        out[0] = (float)((red[0] + red[1] + red[2] + red[3]) * (1.0 / ((double)P * (double)C))
                         + 0.69314718055994531);
}

extern "C" void kernel_launch(void* const* d_in, const int* in_sizes, int n_in,
                              void* d_out, int out_size, void* d_ws, size_t ws_size,
                              hipStream_t stream) {
    const float* prev_feat = (const float*)d_in[0];
    const float* cur_feat  = (const float*)d_in[1];
    const int* prev_ids    = (const int*)d_in[2];
    const int* cur_ids     = (const int*)d_in[3];
    float* out = (float*)d_out;

    char* ws = (char*)d_ws;
    unsigned short* prevb = (unsigned short*)ws;                          // 4 MB
    unsigned short* curb  = (unsigned short*)(ws + (size_t)P * D * 2);    // 4 MB
    float* partial = (float*)(ws + (size_t)(P + C) * D * 2);              // 1 KB

    prep_kernel<<<(P + C) / 4, 256, 0, stream>>>(prev_feat, cur_feat, prevb, curb);
    gemm_bce_kernel<<<256, 512, 0, stream>>>(prevb, curb, prev_ids, cur_ids, partial);
    reduce_kernel<<<1, 256, 0, stream>>>(partial, out);
}

// Round 10
// 56.198 us; speedup vs baseline: 1.2479x; 1.2479x over previous
//
#include <hip/hip_runtime.h>
#include <hip/hip_bf16.h>

typedef __attribute__((ext_vector_type(8))) short bf16x8;
typedef __attribute__((ext_vector_type(4))) float f32x4;
typedef __attribute__((ext_vector_type(2))) float f32x2;

constexpr int P = 8192, C = 8192, D = 256;
constexpr int BM = 256, BN = 256, BK = 64;
constexpr int KT = D / BK;   // 4 K-tiles

__device__ __forceinline__ void gload_lds16(const void* g, void* l) {
    __builtin_amdgcn_global_load_lds((const __attribute__((address_space(1))) void*)g,
                                     (__attribute__((address_space(3))) void*)l, 16, 0, 0);
}

__device__ __forceinline__ unsigned short bfbits(float f) {
    __hip_bfloat16 h = __float2bfloat16(f);
    return __builtin_bit_cast(unsigned short, h);
}

// Normalize rows to unit L2 norm, store bf16. One wave per row, float4 loads.
__global__ __launch_bounds__(256) void prep_kernel(const float* __restrict__ prev,
                                                   const float* __restrict__ cur,
                                                   unsigned short* __restrict__ prevb,
                                                   unsigned short* __restrict__ curb) {
    const int lane = threadIdx.x & 63;
    const int wv = threadIdx.x >> 6;
    const int row = blockIdx.x * 4 + wv;
    const float* src;
    unsigned short* dst;
    int r;
    if (row < P) { src = prev; dst = prevb; r = row; }
    else         { src = cur;  dst = curb;  r = row - P; }
    const float4 v = *(const float4*)(src + (size_t)r * D + lane * 4);
    float ss = v.x * v.x + v.y * v.y + v.z * v.z + v.w * v.w;
#pragma unroll
    for (int off = 32; off; off >>= 1) ss += __shfl_xor(ss, off, 64);
    const float inv = 1.0f / sqrtf(ss);   // norms ~16; eps=1e-6 unreachable
    ushort4 o;
    o.x = bfbits(v.x * inv);
    o.y = bfbits(v.y * inv);
    o.z = bfbits(v.z * inv);
    o.w = bfbits(v.w * inv);
    *(ushort4*)(dst + (size_t)r * D + lane * 4) = o;
}

// m201-geometry GEMM: 256x256 block tile, 8 waves (2M x 4N), wave tile
// 128x64, acc[8][4] in AGPRs (128). BOTH A and B stream through LDS
// (2-buffered K-tiles of BK=64; 128 KB), fragments re-read per phase ->
// persistent regs = acc + ~20 only (r9 failure: persistent/multi-buffered
// operands pushed demand ~290 > 256-reg unified budget -> 38 MB spill).
// Sync is barrier-complete: ONE __syncthreads per K-tile; its implicit
// vmcnt(0) is free (staging issued a full tile earlier); staging writes the
// opposite buffer so intra-tile phases need no barriers. LDS granule swizzle
// pg = g ^ (row&7), source-pre-swizzled, LDS linear (both-sides rule).
// Per CU per K-tile: 256 ds_read_b128 ~3072 cyc vs 512 MFMA ~2483 cyc.
__global__ __attribute__((amdgpu_flat_work_group_size(512, 512), amdgpu_waves_per_eu(2, 2)))
void gemm_bce_kernel(
    const unsigned short* __restrict__ Ab, const unsigned short* __restrict__ Bb,
    const int* __restrict__ pids, const int* __restrict__ cids,
    float* __restrict__ partial) {
    __shared__ short sA[2][BM * BK];   // 2 x 32 KB
    __shared__ short sB[2][BN * BK];   // 2 x 32 KB
    __shared__ float wsum[8];

    const int tid = threadIdx.x;
    const int lane = tid & 63;
    const int wv = tid >> 6;          // 0..7
    const int wm = wv >> 2;           // 0..1
    const int wn = wv & 3;            // 0..3
    const int pblock = blockIdx.y * BM;
    const int cbase = blockIdx.x * BN;

    // Staging: granule G = g*512+tid -> row=G>>3, phys granule pg=G&7;
    // source k-granule = pg ^ (row&7). 4+4 gloads/thread per K-tile.
    auto stage = [&](int kt) {
        const int b = kt & 1;
#pragma unroll
        for (int g = 0; g < 4; ++g) {
            const int G = g * 512 + tid;
            const int row = G >> 3, pg = G & 7;
            const int sk = pg ^ (row & 7);
            gload_lds16(Ab + (size_t)(pblock + row) * D + kt * BK + sk * 8,
                        &sA[b][0] + (size_t)G * 8);
        }
#pragma unroll
        for (int g = 0; g < 4; ++g) {
            const int G = g * 512 + tid;
            const int row = G >> 3, pg = G & 7;
            const int sk = pg ^ (row & 7);
            gload_lds16(Bb + (size_t)(cbase + row) * D + kt * BK + sk * 8,
                        &sB[b][0] + (size_t)G * 8);
        }
    };

    stage(0);
    __syncthreads();   // tile 0 landed (implicit vmcnt(0))

    f32x4 acc[8][4] = {};
    const int fr = lane & 15;     // row within 16-row fragment
    const int fq = lane >> 4;     // k-quarter 0..3

#pragma unroll
    for (int kt = 0; kt < KT; ++kt) {
        const int b = kt & 1;
        if (kt < KT - 1) stage(kt + 1);          // into opposite buffer
        const short* pa = &sA[b][0];
        const short* pb = &sB[b][0];
#pragma unroll
        for (int mh = 0; mh < 2; ++mh)
#pragma unroll
            for (int ks = 0; ks < 2; ++ks) {
                bf16x8 afr[4], bfr[4];
#pragma unroll
                for (int m = 0; m < 4; ++m) {
                    const int row = wm * 128 + mh * 64 + m * 16 + fr;
                    const int pg = (ks * 4 + fq) ^ (row & 7);
                    afr[m] = *(const bf16x8*)(pa + row * 64 + pg * 8);
                }
#pragma unroll
                for (int j = 0; j < 4; ++j) {
                    const int row = wn * 64 + j * 16 + fr;
                    const int pg = (ks * 4 + fq) ^ (row & 7);
                    bfr[j] = *(const bf16x8*)(pb + row * 64 + pg * 8);
                }
#pragma unroll
                for (int m = 0; m < 4; ++m)
#pragma unroll
                    for (int j = 0; j < 4; ++j)
                        acc[mh * 4 + m][j] = __builtin_amdgcn_mfma_f32_16x16x32_bf16(
                            afr[m], bfr[j], acc[mh * 4 + m][j], 0, 0, 0);
            }
        __syncthreads();   // all waves done with buf b; next-next stage may reuse it
    }

    // ---- epilogue: ids loaded HERE (transient regs, once per block) ----
    // C/D layout: col=lane&15, row=(lane>>4)*4+reg (m89-verified).
    int pidp[16];
#pragma unroll
    for (int m = 0; m < 8; ++m)
#pragma unroll
        for (int rp = 0; rp < 2; ++rp) {
            const int base = pblock + wm * 128 + m * 16 + fq * 4 + rp * 2;
            pidp[m * 2 + rp] = (pids[base] & 0xffff) | (pids[base + 1] << 16);
        }
    int cid_r[4];
#pragma unroll
    for (int j = 0; j < 4; ++j) cid_r[j] = cids[cbase + wn * 64 + j * 16 + fr];

    // ln(2cosh(x/2)) - ln2 = t/8 - t^2/192 + t^3/2880 - 17t^4/645120, t=x^2
    constexpr float C1 = 0.125f, C2 = -5.2083333e-3f, C3 = 3.4722222e-4f, C4 = -2.6354832e-5f;
    f32x2 sh2 = {0.f, 0.f}, sx2 = {0.f, 0.f};
#pragma unroll
    for (int m = 0; m < 8; ++m)
#pragma unroll
        for (int j = 0; j < 4; ++j)
#pragma unroll
            for (int rp = 0; rp < 2; ++rp) {
                const f32x2 x = {acc[m][j][rp * 2], acc[m][j][rp * 2 + 1]};
                const f32x2 t2 = x * x;
                f32x2 q = t2 * C4 + C3;
                q = t2 * q + C2;
                q = t2 * q + C1;
                sh2 = t2 * q + sh2;
                const int pp = pidp[m * 2 + rp];
                const f32x2 cc = {
                    ((pp & 0xffff) == cid_r[j]) ? -0.5f : 0.5f,
                    ((pp >> 16)    == cid_r[j]) ? -0.5f : 0.5f};
                sx2 = x * cc + sx2;
            }

    float lsum = sh2.x + sh2.y + sx2.x + sx2.y;
#pragma unroll
    for (int off = 32; off; off >>= 1) lsum += __shfl_xor(lsum, off, 64);
    if (lane == 0) wsum[wv] = lsum;
    __syncthreads();
    if (tid == 0) {
        float bsum = 0.f;
#pragma unroll
        for (int w = 0; w < 8; ++w) bsum += wsum[w];
        partial[blockIdx.y * gridDim.x + blockIdx.x] = bsum;
    }
}

// Deterministic final reduction over 1024 block partials; adds folded ln2.
__global__ __launch_bounds__(256) void reduce_kernel(const float* __restrict__ part,
                                                     float* __restrict__ out) {
    const int tid = threadIdx.x;
    double s = 0.0;
    for (int i = tid; i < 1024; i += 256) s += (double)part[i];
#pragma unroll
    for (int off = 32; off; off >>= 1) s += __shfl_xor(s, off, 64);
    __shared__ double red[4];
    const int lane = tid & 63, wv = tid >> 6;
    if (lane == 0) red[wv] = s;
    __syncthreads();
    if (tid == 0)
        out[0] = (float)((red[0] + red[1] + red[2] + red[3]) * (1.0 / ((double)P * (double)C))
                         + 0.69314718055994531);
}

extern "C" void kernel_launch(void* const* d_in, const int* in_sizes, int n_in,
                              void* d_out, int out_size, void* d_ws, size_t ws_size,
                              hipStream_t stream) {
    const float* prev_feat = (const float*)d_in[0];
    const float* cur_feat  = (const float*)d_in[1];
    const int* prev_ids    = (const int*)d_in[2];
    const int* cur_ids     = (const int*)d_in[3];
    float* out = (float*)d_out;

    char* ws = (char*)d_ws;
    unsigned short* prevb = (unsigned short*)ws;                          // 4 MB
    unsigned short* curb  = (unsigned short*)(ws + (size_t)P * D * 2);    // 4 MB
    float* partial = (float*)(ws + (size_t)(P + C) * D * 2);              // 4 KB

    prep_kernel<<<(P + C) / 4, 256, 0, stream>>>(prev_feat, cur_feat, prevb, curb);
    dim3 grid(C / BN, P / BM);                                            // 32 x 32
    gemm_bce_kernel<<<grid, 512, 0, stream>>>(prevb, curb, prev_ids, cur_ids, partial);
    reduce_kernel<<<1, 256, 0, stream>>>(partial, out);
}